// Round 5
// baseline (272.386 us; speedup 1.0000x reference)
//
#include <hip/hip_runtime.h>

// image (8,256,64,64) f32, boxes (1000,4) f32, box_ind (1000,) i32
// out (1000,256,14,14) f32
constexpr int CROP_H = 14;
constexpr int CROP_W = 14;
constexpr int PIX    = CROP_H * CROP_W;   // 196
constexpr int IMG_C  = 256;
constexpr int IMG_H  = 64;
constexpr int IMG_W  = 64;
constexpr int N_BOX  = 1000;
constexpr int NXCD   = 8;                 // MI355X XCD count
constexpr int CPT    = IMG_C / NXCD;      // 32 channels per thread
constexpr int PIX_BLOCKS = (N_BOX * PIX + 255) / 256;  // 766

// 8B tap loads: (v00,v01) and (v10,v11) are horizontally adjacent, so one
// float2 load each. Pointer is only 4B-aligned -> aligned(4) vector type
// (gfx950 unaligned global access; worst case clang splits into 2 dwords,
// which is identical to the previous kernel). Halves gather instructions
// and L1/TA transaction work, which the round-3 post-mortem indicts as the
// cost above the 33 us write floor.
typedef float f2 __attribute__((ext_vector_type(2), aligned(4)));

__global__ __launch_bounds__(256) void CropAndResize_5669356832751_kernel(
    const float* __restrict__ image,
    const float* __restrict__ boxes,
    const int*   __restrict__ box_ind,
    float* __restrict__ out)
{
    int chunk = blockIdx.x & (NXCD - 1);          // -> XCD id (round-robin mapping)
    int bidp  = blockIdx.x >> 3;                  // pixel-block index
    int tid   = bidp * 256 + threadIdx.x;
    if (tid >= N_BOX * PIX) return;

    // tid -> (n, p=(y,x)); lanes consecutive in p => coalesced stores
    int n = tid / PIX;
    int p = tid - n * PIX;
    int y = p / CROP_W;
    int x = p - y * CROP_W;
    int c0 = chunk * CPT;

    float y1 = boxes[4 * n + 0];
    float x1 = boxes[4 * n + 1];
    float y2 = boxes[4 * n + 2];
    float x2 = boxes[4 * n + 3];
    int   b  = box_ind[n];

    const float hs = (y2 - y1) * (63.0f / 13.0f);
    const float ws = (x2 - x1) * (63.0f / 13.0f);
    float in_y = y1 * 63.0f + (float)y * hs;
    float in_x = x1 * 63.0f + (float)x * ws;

    bool oob = (in_y < 0.0f) | (in_y > 63.0f) | (in_x < 0.0f) | (in_x > 63.0f);

    float tf = floorf(in_y);
    float lf = floorf(in_x);
    int ti = (int)fminf(fmaxf(tf, 0.0f), 63.0f);
    int li = (int)fminf(fmaxf(lf, 0.0f), 63.0f);

    // Shift 2x2 window so all 4 taps are in-bounds at fixed offsets:
    // rows {row0,row0+1}, cols {col0,col0+1}. Effective lerp measured from
    // the window origin reproduces the clamped-tap semantics exactly for
    // in-bounds samples (ti==63 -> in_y==63 -> lerp_eff==1 selects row 63).
    int row0 = min(ti, 62);
    int col0 = min(li, 62);
    float yl = fminf(fmaxf(in_y, 0.0f), 63.0f) - (float)row0;
    float xl = fminf(fmaxf(in_x, 0.0f), 63.0f) - (float)col0;

    // Bilinear weights with OOB mask folded in (OOB -> all zero -> val 0)
    float m    = oob ? 0.0f : 1.0f;
    float omxl = 1.0f - xl;
    float omyl = 1.0f - yl;
    float w00 = omxl * omyl * m;
    float w01 = xl   * omyl * m;
    float w10 = omxl * yl   * m;
    float w11 = xl   * yl   * m;

    const float* src = image + ((size_t)b * IMG_C + c0) * (size_t)(IMG_H * IMG_W)
                             + row0 * IMG_W + col0;
    float* dst = out + ((size_t)n * IMG_C + c0) * (size_t)PIX + p;

#pragma unroll
    for (int c = 0; c < CPT; ++c) {
        f2 t  = *reinterpret_cast<const f2*>(src);          // v00, v01
        f2 bo = *reinterpret_cast<const f2*>(src + IMG_W);  // v10, v11
        float v = t.x * w00 + t.y * w01 + bo.x * w10 + bo.y * w11;
        __builtin_nontemporal_store(v, dst);
        src += IMG_H * IMG_W;
        dst += PIX;
    }
}

extern "C" void kernel_launch(void* const* d_in, const int* in_sizes, int n_in,
                              void* d_out, int out_size, void* d_ws, size_t ws_size,
                              hipStream_t stream) {
    const float* image   = (const float*)d_in[0];
    const float* boxes   = (const float*)d_in[1];
    const int*   box_ind = (const int*)d_in[2];
    float* out = (float*)d_out;

    dim3 grid(PIX_BLOCKS * NXCD);
    CropAndResize_5669356832751_kernel<<<grid, 256, 0, stream>>>(
        image, boxes, box_ind, out);
}

// Round 6
// 270.955 us; speedup vs baseline: 1.0053x; 1.0053x over previous
//
#include <hip/hip_runtime.h>

// image (8,256,64,64) f32, boxes (1000,4) f32, box_ind (1000,) i32
// out (1000,256,14,14) f32
constexpr int CROP_H = 14;
constexpr int CROP_W = 14;
constexpr int PIX    = CROP_H * CROP_W;   // 196
constexpr int IMG_C  = 256;
constexpr int IMG_H  = 64;
constexpr int IMG_W  = 64;
constexpr int N_BOX  = 1000;
constexpr int NXCD   = 8;                 // MI355X XCD count
constexpr int CPT    = IMG_C / NXCD;      // 32 channels per thread
constexpr int BATCH  = 8;                 // channels per load batch (MLP depth)
constexpr int PIX_BLOCKS = (N_BOX * PIX + 255) / 256;  // 766

// Round-5 post-mortem: VGPR_Count=28 shows the channel loop compiled to a
// serial load->wait->fma->store chain (~2 loads in flight/wave). With ~600cy
// scattered-read latency that alone is ~40us of exposed latency. Fix: batch
// 8 channels' tap loads (16 independent f2 loads) into registers before any
// use -> 8x MLP. ~60 VGPR still allows 8 waves/SIMD (full occupancy).
typedef float f2 __attribute__((ext_vector_type(2), aligned(4)));

__global__ __launch_bounds__(256) void CropAndResize_5669356832751_kernel(
    const float* __restrict__ image,
    const float* __restrict__ boxes,
    const int*   __restrict__ box_ind,
    float* __restrict__ out)
{
    int chunk = blockIdx.x & (NXCD - 1);          // -> XCD id (round-robin mapping)
    int bidp  = blockIdx.x >> 3;                  // pixel-block index
    int tid   = bidp * 256 + threadIdx.x;
    if (tid >= N_BOX * PIX) return;

    // tid -> (n, p=(y,x)); lanes consecutive in p => coalesced stores
    int n = tid / PIX;
    int p = tid - n * PIX;
    int y = p / CROP_W;
    int x = p - y * CROP_W;
    int c0 = chunk * CPT;

    float y1 = boxes[4 * n + 0];
    float x1 = boxes[4 * n + 1];
    float y2 = boxes[4 * n + 2];
    float x2 = boxes[4 * n + 3];
    int   b  = box_ind[n];

    const float hs = (y2 - y1) * (63.0f / 13.0f);
    const float ws = (x2 - x1) * (63.0f / 13.0f);
    float in_y = y1 * 63.0f + (float)y * hs;
    float in_x = x1 * 63.0f + (float)x * ws;

    bool oob = (in_y < 0.0f) | (in_y > 63.0f) | (in_x < 0.0f) | (in_x > 63.0f);

    float tf = floorf(in_y);
    float lf = floorf(in_x);
    int ti = (int)fminf(fmaxf(tf, 0.0f), 63.0f);
    int li = (int)fminf(fmaxf(lf, 0.0f), 63.0f);

    // Shift 2x2 window so all 4 taps are in-bounds at fixed offsets:
    // rows {row0,row0+1}, cols {col0,col0+1}. Effective lerp measured from
    // the window origin reproduces the clamped-tap semantics exactly for
    // in-bounds samples (ti==63 -> in_y==63 -> lerp_eff==1 selects row 63).
    int row0 = min(ti, 62);
    int col0 = min(li, 62);
    float yl = fminf(fmaxf(in_y, 0.0f), 63.0f) - (float)row0;
    float xl = fminf(fmaxf(in_x, 0.0f), 63.0f) - (float)col0;

    // Bilinear weights with OOB mask folded in (OOB -> all zero -> val 0)
    float m    = oob ? 0.0f : 1.0f;
    float omxl = 1.0f - xl;
    float omyl = 1.0f - yl;
    float w00 = omxl * omyl * m;
    float w01 = xl   * omyl * m;
    float w10 = omxl * yl   * m;
    float w11 = xl   * yl   * m;

    const float* src = image + ((size_t)b * IMG_C + c0) * (size_t)(IMG_H * IMG_W)
                             + row0 * IMG_W + col0;
    float* dst = out + ((size_t)n * IMG_C + c0) * (size_t)PIX + p;

#pragma unroll
    for (int cb = 0; cb < CPT / BATCH; ++cb) {
        f2 t[BATCH], bo[BATCH];
        // Phase 1: issue all 16 independent loads (no uses in between).
#pragma unroll
        for (int i = 0; i < BATCH; ++i) {
            t[i]  = *reinterpret_cast<const f2*>(src);          // v00, v01
            bo[i] = *reinterpret_cast<const f2*>(src + IMG_W);  // v10, v11
            src += IMG_H * IMG_W;
        }
        // Phase 2: consume and store.
#pragma unroll
        for (int i = 0; i < BATCH; ++i) {
            float v = t[i].x * w00 + t[i].y * w01 + bo[i].x * w10 + bo[i].y * w11;
            __builtin_nontemporal_store(v, dst);
            dst += PIX;
        }
    }
}

extern "C" void kernel_launch(void* const* d_in, const int* in_sizes, int n_in,
                              void* d_out, int out_size, void* d_ws, size_t ws_size,
                              hipStream_t stream) {
    const float* image   = (const float*)d_in[0];
    const float* boxes   = (const float*)d_in[1];
    const int*   box_ind = (const int*)d_in[2];
    float* out = (float*)d_out;

    dim3 grid(PIX_BLOCKS * NXCD);
    CropAndResize_5669356832751_kernel<<<grid, 256, 0, stream>>>(
        image, boxes, box_ind, out);
}